// Round 12
// baseline (242.636 us; speedup 1.0000x reference)
//
#include <hip/hip_runtime.h>
#include <hip/hip_bf16.h>

#define N_NODES 50000
#define N_EDGES 800000
#define IN_CH 1024
#define OUT_CH 256
#define NBLK 196  // ceil(N_NODES/256)

typedef __attribute__((ext_vector_type(8))) short bf16x8;
typedef __attribute__((ext_vector_type(4))) float f32x4;

__device__ inline unsigned short f2bf(float f) {
  union { float f; unsigned int u; } v; v.f = f;
  unsigned int r = v.u + 0x7fffu + ((v.u >> 16) & 1u);
  return (unsigned short)(r >> 16);
}
__device__ inline float bf2f(unsigned short u) {
  union { unsigned int u; float f; } v; v.u = ((unsigned int)u) << 16;
  return v.f;
}

// blocks [0,256): convert W fp32 -> bf16; blocks [256,...): histogram of tar
__global__ __launch_bounds__(256) void prep_hist(const float* __restrict__ W,
                                                 unsigned short* __restrict__ Wb,
                                                 const int* __restrict__ tar,
                                                 int* __restrict__ counts) {
  const int b = blockIdx.x, t = threadIdx.x;
  if (b < 256) {
    const int i4 = (b * 256 + t) * 4;
    float4 f = *(const float4*)(W + i4);
    *(ushort4*)(Wb + i4) = make_ushort4(f2bf(f.x), f2bf(f.y), f2bf(f.z), f2bf(f.w));
  } else {
    const int e = (b - 256) * 256 + t;
    if (e < N_EDGES) atomicAdd(&counts[tar[e]], 1);
  }
}

// Hb[m][n] = bf16( sum_k X[m][k]*W[n][k] + b[n] )
// Round-4 template (best measured: 121us): 64x128 tile, BK=32, grid (782,2),
// 4 waves (2x2), wave tile 32x64, 2-step register prefetch, dbuf LDS.
__global__ __launch_bounds__(256, 4) void gemm_proj(
    const float* __restrict__ X, const unsigned short* __restrict__ Wb,
    const float* __restrict__ bias, unsigned short* __restrict__ Hb)
{
  __shared__ unsigned short lds_a[2][64][32];    // 8 KB
  __shared__ unsigned short lds_b[2][128][32];   // 16 KB

  const int tid  = threadIdx.x;
  const int lane = tid & 63;
  const int w    = tid >> 6;
  const int wr   = w >> 1, wc = w & 1;
  const int gm0  = blockIdx.x * 64;
  const int gn0  = blockIdx.y * 128;

  const int ar = tid >> 3;         // 0..31
  const int ac = (tid & 7) * 4;    // fp32 col
  const int br = tid >> 2;         // 0..63
  const int bc = (tid & 3) * 8;    // bf16 col

  const int arow0 = gm0 + ar, arow1 = gm0 + ar + 32;
  const bool aok0 = arow0 < N_NODES, aok1 = arow1 < N_NODES;
  const float* xp0 = X + (size_t)arow0 * IN_CH + ac;
  const float* xp1 = X + (size_t)arow1 * IN_CH + ac;
  const unsigned short* wp0 = Wb + (size_t)(gn0 + br) * IN_CH + bc;
  const unsigned short* wp1 = Wb + (size_t)(gn0 + br + 64) * IN_CH + bc;

  f32x4 acc[2][4];
  #pragma unroll
  for (int i = 0; i < 2; i++)
    #pragma unroll
    for (int j = 0; j < 4; j++) acc[i][j] = (f32x4)0.0f;

  float4 avA0, avA1, avB0, avB1;
  bf16x8 bvA0, bvA1, bvB0, bvB1;

#define LOADR(KS, AV0, AV1, BV0, BV1)                                          \
  {                                                                            \
    const int k0_ = (KS) * 32;                                                 \
    AV0 = aok0 ? *(const float4*)(xp0 + k0_) : make_float4(0.f, 0.f, 0.f, 0.f);\
    AV1 = aok1 ? *(const float4*)(xp1 + k0_) : make_float4(0.f, 0.f, 0.f, 0.f);\
    BV0 = *(const bf16x8*)(wp0 + k0_);                                         \
    BV1 = *(const bf16x8*)(wp1 + k0_);                                         \
  }

#define WRITER(BUF, AV0, AV1, BV0, BV1)                                        \
  {                                                                            \
    *(ushort4*)&lds_a[BUF][ar][ac] =                                           \
        make_ushort4(f2bf(AV0.x), f2bf(AV0.y), f2bf(AV0.z), f2bf(AV0.w));      \
    *(ushort4*)&lds_a[BUF][ar + 32][ac] =                                      \
        make_ushort4(f2bf(AV1.x), f2bf(AV1.y), f2bf(AV1.z), f2bf(AV1.w));      \
    *(bf16x8*)&lds_b[BUF][br][bc]      = BV0;                                  \
    *(bf16x8*)&lds_b[BUF][br + 64][bc] = BV1;                                  \
  }

#define COMPUTE(BUF)                                                           \
  {                                                                            \
    const int l15_ = lane & 15;                                                \
    const int kb_  = (lane >> 4) * 8;                                          \
    bf16x8 a0 = *(const bf16x8*)&lds_a[BUF][wr * 32 + l15_][kb_];              \
    bf16x8 a1 = *(const bf16x8*)&lds_a[BUF][wr * 32 + 16 + l15_][kb_];         \
    bf16x8 b0 = *(const bf16x8*)&lds_b[BUF][wc * 64 + l15_][kb_];              \
    bf16x8 b1 = *(const bf16x8*)&lds_b[BUF][wc * 64 + 16 + l15_][kb_];         \
    bf16x8 b2 = *(const bf16x8*)&lds_b[BUF][wc * 64 + 32 + l15_][kb_];         \
    bf16x8 b3 = *(const bf16x8*)&lds_b[BUF][wc * 64 + 48 + l15_][kb_];         \
    acc[0][0] = __builtin_amdgcn_mfma_f32_16x16x32_bf16(a0, b0, acc[0][0], 0, 0, 0); \
    acc[0][1] = __builtin_amdgcn_mfma_f32_16x16x32_bf16(a0, b1, acc[0][1], 0, 0, 0); \
    acc[0][2] = __builtin_amdgcn_mfma_f32_16x16x32_bf16(a0, b2, acc[0][2], 0, 0, 0); \
    acc[0][3] = __builtin_amdgcn_mfma_f32_16x16x32_bf16(a0, b3, acc[0][3], 0, 0, 0); \
    acc[1][0] = __builtin_amdgcn_mfma_f32_16x16x32_bf16(a1, b0, acc[1][0], 0, 0, 0); \
    acc[1][1] = __builtin_amdgcn_mfma_f32_16x16x32_bf16(a1, b1, acc[1][1], 0, 0, 0); \
    acc[1][2] = __builtin_amdgcn_mfma_f32_16x16x32_bf16(a1, b2, acc[1][2], 0, 0, 0); \
    acc[1][3] = __builtin_amdgcn_mfma_f32_16x16x32_bf16(a1, b3, acc[1][3], 0, 0, 0); \
  }

  // prologue: step0 -> buf0 (written), step1 -> regs B
  LOADR(0, avA0, avA1, bvA0, bvA1);
  WRITER(0, avA0, avA1, bvA0, bvA1);
  LOADR(1, avB0, avB1, bvB0, bvB1);
  __syncthreads();

  for (int ks = 0; ks < 32; ks += 2) {
    if (ks + 2 < 32) LOADR(ks + 2, avA0, avA1, bvA0, bvA1);
    COMPUTE(0);
    WRITER(1, avB0, avB1, bvB0, bvB1);
    __syncthreads();
    if (ks + 3 < 32) LOADR(ks + 3, avB0, avB1, bvB0, bvB1);
    COMPUTE(1);
    if (ks + 2 < 32) WRITER(0, avA0, avA1, bvA0, bvA1);
    __syncthreads();
  }
#undef LOADR
#undef WRITER
#undef COMPUTE

  // epilogue: C/D layout col = lane&15, row = (lane>>4)*4 + r
  float bj[4];
  #pragma unroll
  for (int j = 0; j < 4; j++)
    bj[j] = bias[gn0 + wc * 64 + j * 16 + (lane & 15)];

  #pragma unroll
  for (int i = 0; i < 2; i++) {
    const int grow_base = gm0 + wr * 32 + i * 16 + ((lane >> 4) << 2);
    #pragma unroll
    for (int r = 0; r < 4; r++) {
      const int grow = grow_base + r;
      if (grow < N_NODES) {
        #pragma unroll
        for (int j = 0; j < 4; j++) {
          const int gcol = gn0 + wc * 64 + j * 16 + (lane & 15);
          Hb[(size_t)grow * OUT_CH + gcol] = f2bf(acc[i][j][r] + bj[j]);
        }
      }
    }
  }
}

// per-block exclusive scan; local-excl to offsets, block total to blocksum
__global__ __launch_bounds__(256) void scan_block(const int* __restrict__ counts,
                                                  int* __restrict__ offsets,
                                                  int* __restrict__ blocksum) {
  __shared__ int wsum[4];
  const int tid = threadIdx.x, lane = tid & 63, wv = tid >> 6;
  const int i = blockIdx.x * 256 + tid;
  const int v = (i < N_NODES) ? counts[i] : 0;
  int s = v;
  #pragma unroll
  for (int off = 1; off < 64; off <<= 1) {
    int t = __shfl_up(s, off, 64);
    if (lane >= off) s += t;
  }
  if (lane == 63) wsum[wv] = s;
  __syncthreads();
  if (tid == 0) {
    int c = 0;
    #pragma unroll
    for (int k = 0; k < 4; k++) { int t = wsum[k]; wsum[k] = c; c += t; }
  }
  __syncthreads();
  const int excl = wsum[wv] + s - v;
  if (i < N_NODES) offsets[i] = excl;
  if (tid == 255) blocksum[blockIdx.x] = excl + v;
}

__global__ __launch_bounds__(256) void scan_sums(int* __restrict__ blocksum,
                                                 int* __restrict__ offsets) {
  __shared__ int wsum[4];
  const int tid = threadIdx.x, lane = tid & 63, wv = tid >> 6;
  const int v = (tid < NBLK) ? blocksum[tid] : 0;
  int s = v;
  #pragma unroll
  for (int off = 1; off < 64; off <<= 1) {
    int t = __shfl_up(s, off, 64);
    if (lane >= off) s += t;
  }
  if (lane == 63) wsum[wv] = s;
  __syncthreads();
  if (tid == 0) {
    int c = 0;
    #pragma unroll
    for (int k = 0; k < 4; k++) { int t = wsum[k]; wsum[k] = c; c += t; }
  }
  __syncthreads();
  const int excl = wsum[wv] + s - v;
  if (tid < NBLK) blocksum[tid] = excl;
  if (tid == 255) offsets[N_NODES] = excl;
}

__global__ __launch_bounds__(256) void finalize_offsets(int* __restrict__ offsets,
                                                        const int* __restrict__ blocksum,
                                                        int* __restrict__ cursor) {
  const int i = blockIdx.x * 256 + threadIdx.x;
  if (i < N_NODES) {
    const int off = offsets[i] + blocksum[i >> 8];
    offsets[i] = off;
    cursor[i] = off;
  }
}

__global__ __launch_bounds__(256) void fill_csr(const int* __restrict__ src,
                                                const int* __restrict__ tar,
                                                const float* __restrict__ ew,
                                                int* __restrict__ cursor,
                                                int2* __restrict__ edata) {
  int e = blockIdx.x * blockDim.x + threadIdx.x;
  if (e >= N_EDGES) return;
  const int t = tar[e];
  const int p = atomicAdd(&cursor[t], 1);
  edata[p] = make_int2(src[e], __float_as_int(ew[e]));
}

// one wave per node: OUT = sw*h_self + sum_e w_e * h_src (16 gathers in flight)
__global__ __launch_bounds__(256) void node_agg(
    const unsigned short* __restrict__ Hb, const int* __restrict__ offsets,
    const int2* __restrict__ edata, const float* __restrict__ sw,
    float* __restrict__ OUT)
{
  const int wid = (blockIdx.x * blockDim.x + threadIdx.x) >> 6;
  if (wid >= N_NODES) return;
  const int lane = threadIdx.x & 63;
  const int e0 = offsets[wid];
  const int e1 = offsets[wid + 1];

  float a0 = 0.f, a1 = 0.f, a2 = 0.f, a3 = 0.f;

  for (int base = e0; base < e1; base += 64) {
    const int avail = e1 - base;
    int2 d = make_int2(0, 0);
    if (lane < avail) d = edata[base + lane];
    const int n = (avail < 64) ? avail : 64;
    int j = 0;
    for (; j + 16 <= n; j += 16) {
      int   sE[16];
      float wE[16];
      #pragma unroll
      for (int q = 0; q < 16; q++) {
        sE[q] = __shfl(d.x, j + q, 64);
        wE[q] = __int_as_float(__shfl(d.y, j + q, 64));
      }
      ushort4 hE[16];
      #pragma unroll
      for (int q = 0; q < 16; q++)
        hE[q] = *(const ushort4*)(Hb + (size_t)sE[q] * OUT_CH + lane * 4);
      #pragma unroll
      for (int q = 0; q < 16; q++) {
        a0 += wE[q] * bf2f(hE[q].x);
        a1 += wE[q] * bf2f(hE[q].y);
        a2 += wE[q] * bf2f(hE[q].z);
        a3 += wE[q] * bf2f(hE[q].w);
      }
    }
    for (; j + 4 <= n; j += 4) {
      int   sE[4];
      float wE[4];
      #pragma unroll
      for (int q = 0; q < 4; q++) {
        sE[q] = __shfl(d.x, j + q, 64);
        wE[q] = __int_as_float(__shfl(d.y, j + q, 64));
      }
      ushort4 hE[4];
      #pragma unroll
      for (int q = 0; q < 4; q++)
        hE[q] = *(const ushort4*)(Hb + (size_t)sE[q] * OUT_CH + lane * 4);
      #pragma unroll
      for (int q = 0; q < 4; q++) {
        a0 += wE[q] * bf2f(hE[q].x);
        a1 += wE[q] * bf2f(hE[q].y);
        a2 += wE[q] * bf2f(hE[q].z);
        a3 += wE[q] * bf2f(hE[q].w);
      }
    }
    for (; j < n; j++) {
      const int   s = __shfl(d.x, j, 64);
      const float wgt = __int_as_float(__shfl(d.y, j, 64));
      const ushort4 h = *(const ushort4*)(Hb + (size_t)s * OUT_CH + lane * 4);
      a0 += wgt * bf2f(h.x); a1 += wgt * bf2f(h.y);
      a2 += wgt * bf2f(h.z); a3 += wgt * bf2f(h.w);
    }
  }

  const float swv = sw[wid];
  const ushort4 hs = *(const ushort4*)(Hb + (size_t)wid * OUT_CH + lane * 4);
  float4 o;
  o.x = a0 + swv * bf2f(hs.x);
  o.y = a1 + swv * bf2f(hs.y);
  o.z = a2 + swv * bf2f(hs.z);
  o.w = a3 + swv * bf2f(hs.w);
  *(float4*)(OUT + (size_t)wid * OUT_CH + lane * 4) = o;
}

extern "C" void kernel_launch(void* const* d_in, const int* in_sizes, int n_in,
                              void* d_out, int out_size, void* d_ws, size_t ws_size,
                              hipStream_t stream) {
  const float* x   = (const float*)d_in[0];
  const float* W   = (const float*)d_in[1];
  const float* b   = (const float*)d_in[2];
  const int*   src = (const int*)d_in[3];
  const int*   tar = (const int*)d_in[4];
  const float* ew  = (const float*)d_in[5];
  const float* sw  = (const float*)d_in[6];
  float* out = (float*)d_out;

  // ws: Wb 0.5MB | Hb 25.6MB | counts | offsets | cursor | blocksum | edata 6.4MB  (~33MB)
  char* ws = (char*)d_ws;
  size_t o = 0;
  unsigned short* Wb = (unsigned short*)(ws + o);
  o += (size_t)OUT_CH * IN_CH * 2;          o = (o + 255) & ~(size_t)255;
  unsigned short* Hb = (unsigned short*)(ws + o);
  o += (size_t)N_NODES * OUT_CH * 2;        o = (o + 255) & ~(size_t)255;
  int* counts   = (int*)(ws + o); o += (size_t)N_NODES * 4;       o = (o + 255) & ~(size_t)255;
  int* offsets  = (int*)(ws + o); o += (size_t)(N_NODES + 1) * 4; o = (o + 255) & ~(size_t)255;
  int* cursor   = (int*)(ws + o); o += (size_t)N_NODES * 4;       o = (o + 255) & ~(size_t)255;
  int* blocksum = (int*)(ws + o); o += (size_t)NBLK * 4;          o = (o + 255) & ~(size_t)255;
  int2* edata   = (int2*)(ws + o);

  hipMemsetAsync(counts, 0, (size_t)N_NODES * 4, stream);
  prep_hist<<<256 + (N_EDGES + 255) / 256, 256, 0, stream>>>(W, Wb, tar, counts);
  scan_block<<<NBLK, 256, 0, stream>>>(counts, offsets, blocksum);
  scan_sums<<<1, 256, 0, stream>>>(blocksum, offsets);
  finalize_offsets<<<NBLK, 256, 0, stream>>>(offsets, blocksum, cursor);
  fill_csr<<<(N_EDGES + 255) / 256, 256, 0, stream>>>(src, tar, ew, cursor, edata);

  dim3 g1((N_NODES + 63) / 64, OUT_CH / 128);
  gemm_proj<<<g1, 256, 0, stream>>>(x, Wb, b, Hb);

  const long long nthreads = (long long)N_NODES * 64;
  node_agg<<<(int)((nthreads + 255) / 256), 256, 0, stream>>>(Hb, offsets, edata, sw, out);
}